// Round 1
// baseline (213.080 us; speedup 1.0000x reference)
//
#include <hip/hip_runtime.h>
#include <cstdint>

// Radix-select layout: 12 + 12 + 8 bits of the (nonnegative) float bit pattern.
// ws layout:
//   [0      .. 16384)  hist1 (4096 u32)
//   [16384  .. 32768)  hist2 (4096 u32)
//   [32768  .. 33792)  hist3 (256 u32)
//   [34816  .. 34832)  SelState
//   [40960  .. 40960 + 4N)  cached uloss bits (optional, if ws_size permits)

struct SelState {
    uint32_t prefix;    // selected high bits so far
    uint32_t k_rem;     // remaining rank within selected bin
    uint32_t thr_bits;  // final threshold bit pattern (valid when done)
    uint32_t done;      // 1 once thr_bits is final
};

// unobserved loss = (t<0) * bce(-x,-t); bce(a,b) = max(a,0) - a*b + log1p(exp(-|a|))
// (-x)*(-t) == x*t exactly in FP; |-x| == |x|. Mirror reference assoc order, no FMA contraction.
__device__ __forceinline__ uint32_t uloss_bits(float x, float t) {
#pragma clang fp contract(off)
    if (t < 0.0f) {
        float nl = (fmaxf(-x, 0.0f) - x * t) + log1pf(expf(-fabsf(x)));
        return __float_as_uint(nl);
    }
    return 0u;
}

__device__ __forceinline__ float final_loss(float x, float t, uint32_t thr) {
#pragma clang fp contract(off)
    float lp = log1pf(expf(-fabsf(x)));
    if (t > 0.0f) {
        return (fmaxf(x, 0.0f) - x * t) + lp;   // positive_loss, mask=1
    }
    if (t < 0.0f) {
        float nl = (fmaxf(-x, 0.0f) - x * t) + lp;  // negative_loss (>0)
        // strict compare vs exact threshold; nonneg floats: uint compare == float compare
        return (__float_as_uint(nl) < thr) ? nl : 0.0f;
    }
    return 0.0f;
}

__global__ __launch_bounds__(256) void hist_pass1(
        const float* __restrict__ x, const float* __restrict__ t,
        uint32_t* __restrict__ uvals, uint32_t* __restrict__ hist, int n) {
    __shared__ uint32_t lh[4096];
    for (int i = threadIdx.x; i < 4096; i += blockDim.x) lh[i] = 0;
    __syncthreads();

    const int n4 = n >> 2;
    const float4* x4 = (const float4*)x;
    const float4* t4 = (const float4*)t;
    const int stride = gridDim.x * blockDim.x;
    for (int i = blockIdx.x * blockDim.x + threadIdx.x; i < n4; i += stride) {
        float4 xv = x4[i];
        float4 tv = t4[i];
        uint32_t u0 = uloss_bits(xv.x, tv.x);
        uint32_t u1 = uloss_bits(xv.y, tv.y);
        uint32_t u2 = uloss_bits(xv.z, tv.z);
        uint32_t u3 = uloss_bits(xv.w, tv.w);
        if (uvals) ((uint4*)uvals)[i] = make_uint4(u0, u1, u2, u3);
        if (tv.x < 0.0f) atomicAdd(&lh[u0 >> 20], 1u);
        if (tv.y < 0.0f) atomicAdd(&lh[u1 >> 20], 1u);
        if (tv.z < 0.0f) atomicAdd(&lh[u2 >> 20], 1u);
        if (tv.w < 0.0f) atomicAdd(&lh[u3 >> 20], 1u);
    }
    if (blockIdx.x == 0) {  // tail
        for (int i = (n4 << 2) + threadIdx.x; i < n; i += blockDim.x) {
            float xx = x[i], tt = t[i];
            uint32_t u = uloss_bits(xx, tt);
            if (uvals) uvals[i] = u;
            if (tt < 0.0f) atomicAdd(&lh[u >> 20], 1u);
        }
    }
    __syncthreads();
    for (int i = threadIdx.x; i < 4096; i += blockDim.x) {
        uint32_t c = lh[i];
        if (c) atomicAdd(&hist[i], c);
    }
}

__global__ __launch_bounds__(256) void hist_refine(
        const float* __restrict__ x, const float* __restrict__ t,
        const uint32_t* __restrict__ uvals, int n,
        const SelState* __restrict__ st, uint32_t* __restrict__ hist,
        int match_shift, int bin_shift, uint32_t bin_mask) {
    __shared__ uint32_t lh[4096];
    SelState s = *st;
    if (s.done) return;                 // uniform across all threads
    const uint32_t prefix = s.prefix;
    for (int i = threadIdx.x; i <= (int)bin_mask; i += blockDim.x) lh[i] = 0;
    __syncthreads();

    const int n4 = n >> 2;
    const int stride = gridDim.x * blockDim.x;
    const int tid0 = blockIdx.x * blockDim.x + threadIdx.x;
    if (uvals) {
        const uint4* u4 = (const uint4*)uvals;
        for (int i = tid0; i < n4; i += stride) {
            uint4 u = u4[i];
            if ((u.x >> match_shift) == prefix) atomicAdd(&lh[(u.x >> bin_shift) & bin_mask], 1u);
            if ((u.y >> match_shift) == prefix) atomicAdd(&lh[(u.y >> bin_shift) & bin_mask], 1u);
            if ((u.z >> match_shift) == prefix) atomicAdd(&lh[(u.z >> bin_shift) & bin_mask], 1u);
            if ((u.w >> match_shift) == prefix) atomicAdd(&lh[(u.w >> bin_shift) & bin_mask], 1u);
        }
        if (blockIdx.x == 0) {
            for (int i = (n4 << 2) + threadIdx.x; i < n; i += blockDim.x) {
                uint32_t u = uvals[i];
                if ((u >> match_shift) == prefix) atomicAdd(&lh[(u >> bin_shift) & bin_mask], 1u);
            }
        }
    } else {
        const float4* x4 = (const float4*)x;
        const float4* t4 = (const float4*)t;
        for (int i = tid0; i < n4; i += stride) {
            float4 xv = x4[i];
            float4 tv = t4[i];
            uint32_t u0 = uloss_bits(xv.x, tv.x);
            uint32_t u1 = uloss_bits(xv.y, tv.y);
            uint32_t u2 = uloss_bits(xv.z, tv.z);
            uint32_t u3 = uloss_bits(xv.w, tv.w);
            if ((u0 >> match_shift) == prefix) atomicAdd(&lh[(u0 >> bin_shift) & bin_mask], 1u);
            if ((u1 >> match_shift) == prefix) atomicAdd(&lh[(u1 >> bin_shift) & bin_mask], 1u);
            if ((u2 >> match_shift) == prefix) atomicAdd(&lh[(u2 >> bin_shift) & bin_mask], 1u);
            if ((u3 >> match_shift) == prefix) atomicAdd(&lh[(u3 >> bin_shift) & bin_mask], 1u);
        }
        if (blockIdx.x == 0) {
            for (int i = (n4 << 2) + threadIdx.x; i < n; i += blockDim.x) {
                uint32_t u = uloss_bits(x[i], t[i]);
                if ((u >> match_shift) == prefix) atomicAdd(&lh[(u >> bin_shift) & bin_mask], 1u);
            }
        }
    }
    __syncthreads();
    for (int i = threadIdx.x; i <= (int)bin_mask; i += blockDim.x) {
        uint32_t c = lh[i];
        if (c) atomicAdd(&hist[i], c);
    }
}

// Single block, 256 threads. Finds the bin containing the k-th LARGEST element.
// level 0: k from kptr, sets prefix/k_rem (or early-finish: k==0 -> thr=+inf, k>total -> thr=0)
// level 1: appends 12 bits; level 2: appends 8 bits and finalizes thr_bits.
__global__ __launch_bounds__(256) void scan_select(
        const uint32_t* __restrict__ hist, int nbins,
        SelState* __restrict__ st, const int* __restrict__ kptr, int level) {
    __shared__ uint32_t part[256];
    __shared__ SelState sst;
    __shared__ uint32_t sk;
    const int tid = threadIdx.x;
    if (tid == 0) {
        sst = *st;
        if (level == 0) {
            int kk = *kptr;
            sk = (kk > 0) ? (uint32_t)kk : 0u;
        } else {
            sk = sst.k_rem;
        }
    }
    __syncthreads();
    if (level > 0 && sst.done) return;
    const uint32_t k = sk;

    const int ch = nbins >> 8;  // bins per thread (16,16,1)
    uint32_t cnt[16];
    uint32_t lsum = 0;
    for (int j = 0; j < ch; ++j) {
        cnt[j] = hist[tid * ch + j];
        lsum += cnt[j];
    }
    part[tid] = lsum;
    __syncthreads();
    // Hillis-Steele inclusive suffix sum: part[t] = sum_{j>=t} lsum_j
    for (int off = 1; off < 256; off <<= 1) {
        uint32_t add = (tid + off < 256) ? part[tid + off] : 0u;
        __syncthreads();
        part[tid] += add;
        __syncthreads();
    }
    const uint32_t total = part[0];

    if (level == 0) {
        if (k == 0) {
            if (tid == 0) { st->done = 1; st->thr_bits = 0x7F800000u; }  // +inf: keep all
            return;
        }
        if (k > total) {
            if (tid == 0) { st->done = 1; st->thr_bits = 0u; }  // thr = 0.0: mask all
            return;
        }
    }

    // elements in bins strictly above my chunk:
    uint32_t A = (tid < 255) ? part[tid + 1] : 0u;
    for (int j = ch - 1; j >= 0; --j) {
        uint32_t c = cnt[j];
        if (A < k && k <= A + c) {  // exactly one thread/bin satisfies this
            uint32_t bin = (uint32_t)(tid * ch + j);
            uint32_t krem = k - A;
            if (level == 0) {
                st->prefix = bin;
                st->k_rem = krem;
            } else if (level == 1) {
                st->prefix = (sst.prefix << 12) | bin;
                st->k_rem = krem;
            } else {
                st->thr_bits = (sst.prefix << 8) | bin;
                st->done = 1;
            }
        }
        A += c;
    }
}

__global__ __launch_bounds__(256) void final_pass(
        const float* __restrict__ x, const float* __restrict__ t,
        const SelState* __restrict__ st, float* __restrict__ out, int n) {
    const uint32_t thr = st->thr_bits;
    const int n4 = n >> 2;
    const float4* x4 = (const float4*)x;
    const float4* t4 = (const float4*)t;
    float4* o4 = (float4*)out;
    const int stride = gridDim.x * blockDim.x;
    for (int i = blockIdx.x * blockDim.x + threadIdx.x; i < n4; i += stride) {
        float4 xv = x4[i];
        float4 tv = t4[i];
        float4 r;
        r.x = final_loss(xv.x, tv.x, thr);
        r.y = final_loss(xv.y, tv.y, thr);
        r.z = final_loss(xv.z, tv.z, thr);
        r.w = final_loss(xv.w, tv.w, thr);
        o4[i] = r;
    }
    if (blockIdx.x == 0) {
        for (int i = (n4 << 2) + threadIdx.x; i < n; i += blockDim.x) {
            out[i] = final_loss(x[i], t[i], thr);
        }
    }
}

extern "C" void kernel_launch(void* const* d_in, const int* in_sizes, int n_in,
                              void* d_out, int out_size, void* d_ws, size_t ws_size,
                              hipStream_t stream) {
    const float* x = (const float*)d_in[0];
    const float* t = (const float*)d_in[1];
    const int* kptr = (const int*)d_in[2];
    float* out = (float*)d_out;
    const int n = in_sizes[0];
    if (n <= 0) return;

    char* ws = (char*)d_ws;
    uint32_t* hist1 = (uint32_t*)(ws + 0);
    uint32_t* hist2 = (uint32_t*)(ws + 16384);
    uint32_t* hist3 = (uint32_t*)(ws + 32768);
    SelState* st = (SelState*)(ws + 34816);
    const bool cached = ws_size >= (size_t)40960 + (size_t)n * 4u;
    uint32_t* uvals = cached ? (uint32_t*)(ws + 40960) : nullptr;

    // zero histograms + state (ws is poisoned 0xAA before every timed call)
    hipMemsetAsync(d_ws, 0, 36864, stream);

    const int n4 = n >> 2;
    int blocks = (n4 + 255) / 256;
    if (blocks > 2048) blocks = 2048;
    if (blocks < 1) blocks = 1;

    hist_pass1<<<blocks, 256, 0, stream>>>(x, t, uvals, hist1, n);
    scan_select<<<1, 256, 0, stream>>>(hist1, 4096, st, kptr, 0);
    hist_refine<<<blocks, 256, 0, stream>>>(x, t, uvals, n, st, hist2, 20, 8, 4095u);
    scan_select<<<1, 256, 0, stream>>>(hist2, 4096, st, kptr, 1);
    hist_refine<<<blocks, 256, 0, stream>>>(x, t, uvals, n, st, hist3, 8, 0, 255u);
    scan_select<<<1, 256, 0, stream>>>(hist3, 256, st, kptr, 2);
    final_pass<<<blocks, 256, 0, stream>>>(x, t, st, out, n);
}